// Round 1
// baseline (732.007 us; speedup 1.0000x reference)
//
#include <hip/hip_runtime.h>
#include <hip/hip_bf16.h>
#include <math.h>

// Problem constants
constexpr int CH = 256;       // input channels
constexpr int CC = 512;       // concat width (H1*C1 + H2*C2)
constexpr int NH = 12;        // total heads (4 + 8)

// ---------------------------------------------------------------------------
// LayerNorm: one wave per row (256 ch -> 4 floats/lane, one float4)
// ---------------------------------------------------------------------------
__global__ void ln_kernel(const float* __restrict__ x, const float* __restrict__ gamma,
                          const float* __restrict__ beta, float* __restrict__ xn, int N) {
    int wid = (blockIdx.x * blockDim.x + threadIdx.x) >> 6;
    int lane = threadIdx.x & 63;
    if (wid >= N) return;
    const float4 v = *(const float4*)(x + (size_t)wid * CH + lane * 4);
    float s = v.x + v.y + v.z + v.w;
    float sq = v.x * v.x + v.y * v.y + v.z * v.z + v.w * v.w;
    #pragma unroll
    for (int o = 32; o; o >>= 1) { s += __shfl_xor(s, o); sq += __shfl_xor(sq, o); }
    float mu = s * (1.0f / CH);
    float var = sq * (1.0f / CH) - mu * mu;
    float rs = rsqrtf(var + 1e-5f);
    float4 g = *(const float4*)(gamma + lane * 4);
    float4 b = *(const float4*)(beta + lane * 4);
    float4 o4;
    o4.x = (v.x - mu) * rs * g.x + b.x;
    o4.y = (v.y - mu) * rs * g.y + b.y;
    o4.z = (v.z - mu) * rs * g.z + b.z;
    o4.w = (v.w - mu) * rs * g.w + b.w;
    *(float4*)(xn + (size_t)wid * CH + lane * 4) = o4;
}

// ---------------------------------------------------------------------------
// GEMM1: h = x_norm @ [W1 | W2]   ([N,256] x [256,512])
// 128x128 tile, 256 threads, 8x8 per thread (split 4+4 at distance 64)
// ---------------------------------------------------------------------------
__global__ __launch_bounds__(256) void gemm1_kernel(
    const float* __restrict__ A, const float* __restrict__ W1,
    const float* __restrict__ W2, float* __restrict__ C, int M) {
    __shared__ float As[16][128];
    __shared__ float Bs[16][128];
    const int t = threadIdx.x;
    const int tx = t & 15, ty = t >> 4;
    const int m0 = blockIdx.y * 128;
    const int n0 = blockIdx.x * 128;
    const float* B = (n0 < 256) ? (W1 + n0) : (W2 + (n0 - 256));

    float4 acc[2][2][4];
    #pragma unroll
    for (int a = 0; a < 2; ++a)
        #pragma unroll
        for (int b = 0; b < 2; ++b)
            #pragma unroll
            for (int i = 0; i < 4; ++i) acc[a][b][i] = make_float4(0.f, 0.f, 0.f, 0.f);

    const int ar0 = t >> 2;          // rows 0..63
    const int ar1 = ar0 + 64;        // rows 64..127
    const int akq = (t & 3) * 4;     // k sub-offset
    const int bk0 = t >> 5;          // 0..7
    const int bk1 = bk0 + 8;
    const int bnq = (t & 31) * 4;

    const int gr0 = min(m0 + ar0, M - 1);
    const int gr1 = min(m0 + ar1, M - 1);

    for (int k0 = 0; k0 < 256; k0 += 16) {
        float4 a0 = *(const float4*)(A + (size_t)gr0 * 256 + k0 + akq);
        float4 a1 = *(const float4*)(A + (size_t)gr1 * 256 + k0 + akq);
        float4 b0 = *(const float4*)(B + (size_t)(k0 + bk0) * 256 + bnq);
        float4 b1 = *(const float4*)(B + (size_t)(k0 + bk1) * 256 + bnq);
        As[akq + 0][ar0] = a0.x; As[akq + 1][ar0] = a0.y; As[akq + 2][ar0] = a0.z; As[akq + 3][ar0] = a0.w;
        As[akq + 0][ar1] = a1.x; As[akq + 1][ar1] = a1.y; As[akq + 2][ar1] = a1.z; As[akq + 3][ar1] = a1.w;
        *(float4*)&Bs[bk0][bnq] = b0;
        *(float4*)&Bs[bk1][bnq] = b1;
        __syncthreads();
        #pragma unroll
        for (int kk = 0; kk < 16; ++kk) {
            const float4 alo = *(const float4*)&As[kk][ty * 4];
            const float4 ahi = *(const float4*)&As[kk][64 + ty * 4];
            const float4 blo = *(const float4*)&Bs[kk][tx * 4];
            const float4 bhi = *(const float4*)&Bs[kk][64 + tx * 4];
            const float ar[2][4] = {{alo.x, alo.y, alo.z, alo.w}, {ahi.x, ahi.y, ahi.z, ahi.w}};
            const float4 bc[2] = {blo, bhi};
            #pragma unroll
            for (int rh = 0; rh < 2; ++rh)
                #pragma unroll
                for (int i = 0; i < 4; ++i) {
                    float a = ar[rh][i];
                    #pragma unroll
                    for (int cb = 0; cb < 2; ++cb) {
                        acc[rh][cb][i].x += a * bc[cb].x;
                        acc[rh][cb][i].y += a * bc[cb].y;
                        acc[rh][cb][i].z += a * bc[cb].z;
                        acc[rh][cb][i].w += a * bc[cb].w;
                    }
                }
        }
        __syncthreads();
    }
    #pragma unroll
    for (int rh = 0; rh < 2; ++rh)
        #pragma unroll
        for (int i = 0; i < 4; ++i) {
            int r = m0 + rh * 64 + ty * 4 + i;
            if (r < M) {
                *(float4*)(C + (size_t)r * CC + n0 + tx * 4) = acc[rh][0][i];
                *(float4*)(C + (size_t)r * CC + n0 + 64 + tx * 4) = acc[rh][1][i];
            }
        }
}

// ---------------------------------------------------------------------------
// GEMM2: out = x + x_cat @ Wu + bu   ([N,512] x [512,256])
// ---------------------------------------------------------------------------
__global__ __launch_bounds__(256) void gemm2_kernel(
    const float* __restrict__ A, const float* __restrict__ Wu,
    const float* __restrict__ bu, const float* __restrict__ xres,
    float* __restrict__ C, int M) {
    __shared__ float As[16][128];
    __shared__ float Bs[16][128];
    const int t = threadIdx.x;
    const int tx = t & 15, ty = t >> 4;
    const int m0 = blockIdx.y * 128;
    const int n0 = blockIdx.x * 128;
    const float* B = Wu + n0;

    float4 acc[2][2][4];
    #pragma unroll
    for (int a = 0; a < 2; ++a)
        #pragma unroll
        for (int b = 0; b < 2; ++b)
            #pragma unroll
            for (int i = 0; i < 4; ++i) acc[a][b][i] = make_float4(0.f, 0.f, 0.f, 0.f);

    const int ar0 = t >> 2;
    const int ar1 = ar0 + 64;
    const int akq = (t & 3) * 4;
    const int bk0 = t >> 5;
    const int bk1 = bk0 + 8;
    const int bnq = (t & 31) * 4;

    const int gr0 = min(m0 + ar0, M - 1);
    const int gr1 = min(m0 + ar1, M - 1);

    for (int k0 = 0; k0 < 512; k0 += 16) {
        float4 a0 = *(const float4*)(A + (size_t)gr0 * CC + k0 + akq);
        float4 a1 = *(const float4*)(A + (size_t)gr1 * CC + k0 + akq);
        float4 b0 = *(const float4*)(B + (size_t)(k0 + bk0) * 256 + bnq);
        float4 b1 = *(const float4*)(B + (size_t)(k0 + bk1) * 256 + bnq);
        As[akq + 0][ar0] = a0.x; As[akq + 1][ar0] = a0.y; As[akq + 2][ar0] = a0.z; As[akq + 3][ar0] = a0.w;
        As[akq + 0][ar1] = a1.x; As[akq + 1][ar1] = a1.y; As[akq + 2][ar1] = a1.z; As[akq + 3][ar1] = a1.w;
        *(float4*)&Bs[bk0][bnq] = b0;
        *(float4*)&Bs[bk1][bnq] = b1;
        __syncthreads();
        #pragma unroll
        for (int kk = 0; kk < 16; ++kk) {
            const float4 alo = *(const float4*)&As[kk][ty * 4];
            const float4 ahi = *(const float4*)&As[kk][64 + ty * 4];
            const float4 blo = *(const float4*)&Bs[kk][tx * 4];
            const float4 bhi = *(const float4*)&Bs[kk][64 + tx * 4];
            const float ar[2][4] = {{alo.x, alo.y, alo.z, alo.w}, {ahi.x, ahi.y, ahi.z, ahi.w}};
            const float4 bc[2] = {blo, bhi};
            #pragma unroll
            for (int rh = 0; rh < 2; ++rh)
                #pragma unroll
                for (int i = 0; i < 4; ++i) {
                    float a = ar[rh][i];
                    #pragma unroll
                    for (int cb = 0; cb < 2; ++cb) {
                        acc[rh][cb][i].x += a * bc[cb].x;
                        acc[rh][cb][i].y += a * bc[cb].y;
                        acc[rh][cb][i].z += a * bc[cb].z;
                        acc[rh][cb][i].w += a * bc[cb].w;
                    }
                }
        }
        __syncthreads();
    }
    const float4 bu_lo = *(const float4*)(bu + n0 + tx * 4);
    const float4 bu_hi = *(const float4*)(bu + n0 + 64 + tx * 4);
    #pragma unroll
    for (int rh = 0; rh < 2; ++rh)
        #pragma unroll
        for (int i = 0; i < 4; ++i) {
            int r = m0 + rh * 64 + ty * 4 + i;
            if (r < M) {
                float4 xlo = *(const float4*)(xres + (size_t)r * 256 + n0 + tx * 4);
                float4 xhi = *(const float4*)(xres + (size_t)r * 256 + n0 + 64 + tx * 4);
                float4 olo, ohi;
                olo.x = acc[rh][0][i].x + bu_lo.x + xlo.x;
                olo.y = acc[rh][0][i].y + bu_lo.y + xlo.y;
                olo.z = acc[rh][0][i].z + bu_lo.z + xlo.z;
                olo.w = acc[rh][0][i].w + bu_lo.w + xlo.w;
                ohi.x = acc[rh][1][i].x + bu_hi.x + xhi.x;
                ohi.y = acc[rh][1][i].y + bu_hi.y + xhi.y;
                ohi.z = acc[rh][1][i].z + bu_hi.z + xhi.z;
                ohi.w = acc[rh][1][i].w + bu_hi.w + xhi.w;
                *(float4*)(C + (size_t)r * 256 + n0 + tx * 4) = olo;
                *(float4*)(C + (size_t)r * 256 + n0 + 64 + tx * 4) = ohi;
            }
        }
}

// ---------------------------------------------------------------------------
// Per-node attention logits: alpha_src/dst[N,12] (heads 0-3: GAT1, 4-11: GAT2)
// one wave per node; lane covers 8 channels of h[n,512]
// ---------------------------------------------------------------------------
__global__ void alpha_kernel(const float* __restrict__ h,
                             const float* __restrict__ as1, const float* __restrict__ ad1,
                             const float* __restrict__ as2, const float* __restrict__ ad2,
                             float* __restrict__ alpha_src, float* __restrict__ alpha_dst, int N) {
    int wid = (blockIdx.x * blockDim.x + threadIdx.x) >> 6;
    int lane = threadIdx.x & 63;
    if (wid >= N) return;
    int c0 = lane * 8;
    const float* av_s = (c0 < 256) ? (as1 + c0) : (as2 + (c0 - 256));
    const float* av_d = (c0 < 256) ? (ad1 + c0) : (ad2 + (c0 - 256));
    const float4* hp = (const float4*)(h + (size_t)wid * CC + c0);
    float4 h0 = hp[0], h1 = hp[1];
    float4 s0 = *(const float4*)(av_s), s1 = *(const float4*)(av_s + 4);
    float4 d0 = *(const float4*)(av_d), d1 = *(const float4*)(av_d + 4);
    float ps = h0.x * s0.x + h0.y * s0.y + h0.z * s0.z + h0.w * s0.w
             + h1.x * s1.x + h1.y * s1.y + h1.z * s1.z + h1.w * s1.w;
    float pd = h0.x * d0.x + h0.y * d0.y + h0.z * d0.z + h0.w * d0.w
             + h1.x * d1.x + h1.y * d1.y + h1.z * d1.z + h1.w * d1.w;
    ps += __shfl_xor(ps, 1); pd += __shfl_xor(pd, 1);
    ps += __shfl_xor(ps, 2); pd += __shfl_xor(pd, 2);
    float ps3 = ps + __shfl_xor(ps, 4);
    float pd3 = pd + __shfl_xor(pd, 4);
    if (lane < 32) {
        if ((lane & 7) == 0) {
            int hd = lane >> 3;
            alpha_src[(size_t)wid * NH + hd] = ps3;
            alpha_dst[(size_t)wid * NH + hd] = pd3;
        }
    } else {
        if ((lane & 3) == 0) {
            int hd = 4 + ((lane - 32) >> 2);
            alpha_src[(size_t)wid * NH + hd] = ps;
            alpha_dst[(size_t)wid * NH + hd] = pd;
        }
    }
}

// ---------------------------------------------------------------------------
// CSR build
// ---------------------------------------------------------------------------
__global__ void deg_init_kernel(int* __restrict__ deg, int N) {
    int i = blockIdx.x * blockDim.x + threadIdx.x;
    if (i < N) deg[i] = 1;   // self-loop
}

__global__ void hist_kernel(const int* __restrict__ dst, int* __restrict__ deg, int E) {
    int i = blockIdx.x * blockDim.x + threadIdx.x;
    if (i < E) atomicAdd(&deg[dst[i]], 1);
}

__global__ void scan_kernel(const int* __restrict__ deg, int* __restrict__ offsets, int n) {
    __shared__ int buf[1024];
    __shared__ int carry;
    int t = threadIdx.x;
    if (t == 0) { carry = 0; offsets[0] = 0; }
    __syncthreads();
    for (int base = 0; base < n; base += 1024) {
        int v = (base + t < n) ? deg[base + t] : 0;
        buf[t] = v;
        __syncthreads();
        for (int off = 1; off < 1024; off <<= 1) {
            int add = (t >= off) ? buf[t - off] : 0;
            __syncthreads();
            buf[t] += add;
            __syncthreads();
        }
        int incl = buf[t] + carry;
        if (base + t < n) offsets[base + t + 1] = incl;
        __syncthreads();
        if (t == 1023) carry = incl;
        __syncthreads();
    }
}

__global__ void csr_init_kernel(const int* __restrict__ offsets, int* __restrict__ cursor,
                                int* __restrict__ csr, int N) {
    int i = blockIdx.x * blockDim.x + threadIdx.x;
    if (i < N) {
        int o = offsets[i];
        cursor[i] = o + 1;
        csr[o] = i;     // self-loop in slot 0
    }
}

__global__ void scatter_kernel(const int* __restrict__ src, const int* __restrict__ dst,
                               int* __restrict__ cursor, int* __restrict__ csr, int E) {
    int i = blockIdx.x * blockDim.x + threadIdx.x;
    if (i < E) {
        int d = dst[i];
        int pos = atomicAdd(&cursor[d], 1);
        csr[pos] = src[i];
    }
}

// ---------------------------------------------------------------------------
// Aggregation: one wave per node. Lanes 0-11 do per-head softmax stats,
// then all 64 lanes accumulate w * h[src] over the node's in-edges.
// Epilogue: +bias, ELU -> x_cat
// ---------------------------------------------------------------------------
__global__ void aggregate_kernel(const float* __restrict__ h,
                                 const float* __restrict__ alpha_src,
                                 const float* __restrict__ alpha_dst,
                                 const int* __restrict__ offsets,
                                 const int* __restrict__ csr,
                                 const float* __restrict__ b1, const float* __restrict__ b2,
                                 float* __restrict__ xcat, int N) {
    int n = (blockIdx.x * blockDim.x + threadIdx.x) >> 6;
    int lane = threadIdx.x & 63;
    if (n >= N) return;
    int beg = offsets[n], end = offsets[n + 1];

    // phase A: per-head max and sum-exp (lanes 0..11, head = lane)
    float m = -1e30f, ssum = 0.f;
    if (lane < NH) {
        float ad = alpha_dst[(size_t)n * NH + lane];
        for (int i = beg; i < end; ++i) {
            int s = csr[i];
            float lr = alpha_src[(size_t)s * NH + lane] + ad;
            lr = lr > 0.f ? lr : 0.2f * lr;
            m = fmaxf(m, lr);
        }
        for (int i = beg; i < end; ++i) {
            int s = csr[i];
            float lr = alpha_src[(size_t)s * NH + lane] + ad;
            lr = lr > 0.f ? lr : 0.2f * lr;
            ssum += __expf(lr - m);
        }
    }
    int c0 = lane * 8;
    int hid = (lane < 32) ? (lane >> 3) : (4 + ((lane - 32) >> 2));
    float mh = __shfl(m, hid);
    float dh = __shfl(ssum, hid);
    float inv = 1.0f / (dh + 1e-16f);
    float adh = alpha_dst[(size_t)n * NH + hid];

    float4 acc0 = make_float4(0.f, 0.f, 0.f, 0.f);
    float4 acc1 = make_float4(0.f, 0.f, 0.f, 0.f);
    for (int i = beg; i < end; ++i) {
        int s = csr[i];
        float lr = alpha_src[(size_t)s * NH + hid] + adh;
        lr = lr > 0.f ? lr : 0.2f * lr;
        float w = __expf(lr - mh) * inv;
        const float4* hp = (const float4*)(h + (size_t)s * CC + c0);
        float4 h0 = hp[0], h1 = hp[1];
        acc0.x += w * h0.x; acc0.y += w * h0.y; acc0.z += w * h0.z; acc0.w += w * h0.w;
        acc1.x += w * h1.x; acc1.y += w * h1.y; acc1.z += w * h1.z; acc1.w += w * h1.w;
    }
    // epilogue: + bias, ELU
    const float* bb = (c0 < 256) ? (b1 + c0) : (b2 + (c0 - 256));
    float4 bb0 = *(const float4*)(bb), bb1 = *(const float4*)(bb + 4);
    float o[8];
    o[0] = acc0.x + bb0.x; o[1] = acc0.y + bb0.y; o[2] = acc0.z + bb0.z; o[3] = acc0.w + bb0.w;
    o[4] = acc1.x + bb1.x; o[5] = acc1.y + bb1.y; o[6] = acc1.z + bb1.z; o[7] = acc1.w + bb1.w;
    #pragma unroll
    for (int j = 0; j < 8; ++j) o[j] = o[j] > 0.f ? o[j] : expm1f(o[j]);
    float4 w0 = make_float4(o[0], o[1], o[2], o[3]);
    float4 w1 = make_float4(o[4], o[5], o[6], o[7]);
    *(float4*)(xcat + (size_t)n * CC + c0) = w0;
    *(float4*)(xcat + (size_t)n * CC + c0 + 4) = w1;
}

// ---------------------------------------------------------------------------
// Launch
// ---------------------------------------------------------------------------
extern "C" void kernel_launch(void* const* d_in, const int* in_sizes, int n_in,
                              void* d_out, int out_size, void* d_ws, size_t ws_size,
                              hipStream_t stream) {
    const float* x     = (const float*)d_in[0];
    const int*   ei    = (const int*)d_in[1];
    const float* gamma = (const float*)d_in[2];
    const float* beta  = (const float*)d_in[3];
    const float* W1    = (const float*)d_in[4];
    const float* as1   = (const float*)d_in[5];
    const float* ad1   = (const float*)d_in[6];
    const float* b1    = (const float*)d_in[7];
    const float* W2    = (const float*)d_in[8];
    const float* as2   = (const float*)d_in[9];
    const float* ad2   = (const float*)d_in[10];
    const float* b2    = (const float*)d_in[11];
    const float* Wu    = (const float*)d_in[12];
    const float* bu    = (const float*)d_in[13];
    float* out = (float*)d_out;

    const int N = in_sizes[0] / CH;
    const int E = in_sizes[1] / 2;
    const int* src = ei;
    const int* dst = ei + E;

    char* w = (char*)d_ws;
    float* h = (float*)w;          w += (size_t)N * CC * 4;
    float* xcat = (float*)w;       w += (size_t)N * CC * 4;   // x_norm aliases first N*256 floats
    float* xnorm = xcat;
    float* alpha_src = (float*)w;  w += (size_t)N * NH * 4;
    float* alpha_dst = (float*)w;  w += (size_t)N * NH * 4;
    int* deg = (int*)w;            w += (size_t)N * 4;
    int* offsets = (int*)w;        w += ((size_t)N + 4) * 4;
    int* cursor = (int*)w;         w += (size_t)N * 4;
    int* csr = (int*)w;            // E + N entries

    ln_kernel<<<(N + 3) / 4, 256, 0, stream>>>(x, gamma, beta, xnorm, N);

    dim3 g1(4, (N + 127) / 128);
    gemm1_kernel<<<g1, 256, 0, stream>>>(xnorm, W1, W2, h, N);

    alpha_kernel<<<(N + 3) / 4, 256, 0, stream>>>(h, as1, ad1, as2, ad2, alpha_src, alpha_dst, N);

    deg_init_kernel<<<(N + 255) / 256, 256, 0, stream>>>(deg, N);
    hist_kernel<<<(E + 255) / 256, 256, 0, stream>>>(dst, deg, E);
    scan_kernel<<<1, 1024, 0, stream>>>(deg, offsets, N);
    csr_init_kernel<<<(N + 255) / 256, 256, 0, stream>>>(offsets, cursor, csr, N);
    scatter_kernel<<<(E + 255) / 256, 256, 0, stream>>>(src, dst, cursor, csr, E);

    aggregate_kernel<<<(N + 3) / 4, 256, 0, stream>>>(h, alpha_src, alpha_dst, offsets, csr,
                                                      b1, b2, xcat, N);

    dim3 g2(2, (N + 127) / 128);
    gemm2_kernel<<<g2, 256, 0, stream>>>(xcat, Wu, bu, x, out, N);
}

// Round 2
// 292.544 us; speedup vs baseline: 2.5022x; 2.5022x over previous
//
#include <hip/hip_runtime.h>
#include <hip/hip_bf16.h>
#include <math.h>

constexpr int CH = 256;       // input channels
constexpr int CC = 512;       // concat width
constexpr int NH = 12;        // total heads (4 + 8)

typedef __bf16 bf16x8 __attribute__((ext_vector_type(8)));
typedef float  f32x4  __attribute__((ext_vector_type(4)));
typedef __attribute__((address_space(3))) void lds_void;
typedef __attribute__((address_space(1))) void glb_void;

__device__ inline unsigned short f2bf(float f) {
    union { float f; unsigned u; } v; v.f = f;
    unsigned r = v.u + 0x7FFFu + ((v.u >> 16) & 1u);
    return (unsigned short)(r >> 16);
}
__device__ inline float bfbits(unsigned lo16) {
    union { unsigned u; float f; } v; v.u = lo16 << 16;
    return v.f;
}

// ---------------------------------------------------------------------------
// LayerNorm -> bf16: one wave per row
// ---------------------------------------------------------------------------
__global__ void ln_kernel(const float* __restrict__ x, const float* __restrict__ gamma,
                          const float* __restrict__ beta, unsigned short* __restrict__ xnb, int N) {
    int wid = (blockIdx.x * blockDim.x + threadIdx.x) >> 6;
    int lane = threadIdx.x & 63;
    if (wid >= N) return;
    const float4 v = *(const float4*)(x + (size_t)wid * CH + lane * 4);
    float s = v.x + v.y + v.z + v.w;
    float sq = v.x * v.x + v.y * v.y + v.z * v.z + v.w * v.w;
    #pragma unroll
    for (int o = 32; o; o >>= 1) { s += __shfl_xor(s, o); sq += __shfl_xor(sq, o); }
    float mu = s * (1.0f / CH);
    float var = sq * (1.0f / CH) - mu * mu;
    float rs = rsqrtf(var + 1e-5f);
    float4 g = *(const float4*)(gamma + lane * 4);
    float4 b = *(const float4*)(beta + lane * 4);
    unsigned short o0 = f2bf((v.x - mu) * rs * g.x + b.x);
    unsigned short o1 = f2bf((v.y - mu) * rs * g.y + b.y);
    unsigned short o2 = f2bf((v.z - mu) * rs * g.z + b.z);
    unsigned short o3 = f2bf((v.w - mu) * rs * g.w + b.w);
    uint2 pk;
    pk.x = (unsigned)o0 | ((unsigned)o1 << 16);
    pk.y = (unsigned)o2 | ((unsigned)o3 << 16);
    *(uint2*)(xnb + (size_t)wid * CH + lane * 4) = pk;
}

// ---------------------------------------------------------------------------
// Weight prep: transpose + convert to bf16
// WT1 [512][256]: row n = output col n of [W1|W2];  WTu [256][512]
// ---------------------------------------------------------------------------
__global__ void prep_wt1_kernel(const float* __restrict__ W1, const float* __restrict__ W2,
                                unsigned short* __restrict__ WT) {
    int idx = blockIdx.x * 256 + threadIdx.x;      // over 512*256
    if (idx >= 512 * 256) return;
    int n = idx >> 8, k = idx & 255;
    float v = (n < 256) ? W1[(size_t)k * 256 + n] : W2[(size_t)k * 256 + (n - 256)];
    WT[idx] = f2bf(v);
}
__global__ void prep_wtu_kernel(const float* __restrict__ Wu, unsigned short* __restrict__ WT) {
    int idx = blockIdx.x * 256 + threadIdx.x;      // over 256*512
    if (idx >= 256 * 512) return;
    int n = idx >> 9, k = idx & 511;
    WT[idx] = f2bf(Wu[(size_t)k * 256 + n]);
}

// ---------------------------------------------------------------------------
// bf16 MFMA GEMM, 128x128 tile, BK=64, 4 waves (each 64x64 out)
// A [M,K] bf16 row-major, Bt [Ntot,K] bf16 row-major (= B transposed)
// LDS XOR-swizzle: physical colbyte = logical ^ ((row&7)<<4); staged via
// inverse-swizzled global source (global_load_lds writes linearly).
// ---------------------------------------------------------------------------
__device__ inline void gemm_core(const unsigned short* __restrict__ Ab,
                                 const unsigned short* __restrict__ Bt,
                                 unsigned short* As, unsigned short* Bs,
                                 f32x4 acc[4][4], int m0, int n0, int M, int K) {
    const int t = threadIdx.x;
    const int lane = t & 63;
    const int wave = t >> 6;
    const int wr = wave >> 1, wc = wave & 1;
    const int srow = lane >> 3;                        // 0..7
    const int scol = (((lane & 7) ^ srow) << 3);       // inverse-swizzled elem col
    const int fr = lane & 15;
    const int fkb = (lane >> 4) << 4;                  // logical colbyte per 16-lane group

    for (int k0 = 0; k0 < K; k0 += 64) {
        __syncthreads();
        #pragma unroll
        for (int c = 0; c < 4; ++c) {
            int chunk = c * 4 + wave;                  // 0..15 -> 8 rows each
            int row = chunk * 8 + srow;                // 0..127
            int gra = m0 + row; if (gra >= M) gra = M - 1;
            const unsigned short* ga = Ab + (size_t)gra * K + k0 + scol;
            __builtin_amdgcn_global_load_lds((const glb_void*)ga,
                                             (lds_void*)&As[chunk * 512], 16, 0, 0);
            const unsigned short* gb = Bt + (size_t)(n0 + row) * K + k0 + scol;
            __builtin_amdgcn_global_load_lds((const glb_void*)gb,
                                             (lds_void*)&Bs[chunk * 512], 16, 0, 0);
        }
        __syncthreads();
        #pragma unroll
        for (int ks = 0; ks < 2; ++ks) {
            bf16x8 af[4], bfr[4];
            #pragma unroll
            for (int m = 0; m < 4; ++m) {
                int r = wr * 64 + m * 16 + fr;
                int cb = (ks * 64 + fkb) ^ ((r & 7) << 4);
                af[m] = *(const bf16x8*)((const char*)As + r * 128 + cb);
            }
            #pragma unroll
            for (int n = 0; n < 4; ++n) {
                int r = wc * 64 + n * 16 + fr;
                int cb = (ks * 64 + fkb) ^ ((r & 7) << 4);
                bfr[n] = *(const bf16x8*)((const char*)Bs + r * 128 + cb);
            }
            #pragma unroll
            for (int m = 0; m < 4; ++m)
                #pragma unroll
                for (int n = 0; n < 4; ++n)
                    acc[m][n] = __builtin_amdgcn_mfma_f32_16x16x32_bf16(af[m], bfr[n], acc[m][n], 0, 0, 0);
        }
    }
}

// GEMM1: h(bf16)[M,512] = xnorm(bf16)[M,256] @ W(bf16,T)[512,256]^T
__global__ __launch_bounds__(256) void gemm1_mfma(const unsigned short* __restrict__ Ab,
                                                  const unsigned short* __restrict__ Bt,
                                                  unsigned short* __restrict__ H, int M) {
    __shared__ unsigned short As[128 * 64];
    __shared__ unsigned short Bs[128 * 64];
    const int lane = threadIdx.x & 63;
    const int wave = threadIdx.x >> 6;
    const int wr = wave >> 1, wc = wave & 1;
    const int m0 = blockIdx.y * 128, n0 = blockIdx.x * 128;
    f32x4 acc[4][4] = {};
    gemm_core(Ab, Bt, As, Bs, acc, m0, n0, M, 256);
    const int fr = lane & 15;
    const int orow = (lane >> 4) * 4;
    #pragma unroll
    for (int m = 0; m < 4; ++m)
        #pragma unroll
        for (int j = 0; j < 4; ++j) {
            int r = m0 + wr * 64 + m * 16 + orow + j;
            if (r < M) {
                #pragma unroll
                for (int n = 0; n < 4; ++n) {
                    int ccol = n0 + wc * 64 + n * 16 + fr;
                    H[(size_t)r * CC + ccol] = f2bf(acc[m][n][j]);
                }
            }
        }
}

// GEMM2: out(f32)[M,256] = x + xcat(bf16)[M,512] @ Wu(bf16,T)[256,512]^T + bu
__global__ __launch_bounds__(256) void gemm2_mfma(const unsigned short* __restrict__ Ab,
                                                  const unsigned short* __restrict__ Bt,
                                                  const float* __restrict__ bu,
                                                  const float* __restrict__ xres,
                                                  float* __restrict__ C, int M) {
    __shared__ unsigned short As[128 * 64];
    __shared__ unsigned short Bs[128 * 64];
    const int lane = threadIdx.x & 63;
    const int wave = threadIdx.x >> 6;
    const int wr = wave >> 1, wc = wave & 1;
    const int m0 = blockIdx.y * 128, n0 = blockIdx.x * 128;
    f32x4 acc[4][4] = {};
    gemm_core(Ab, Bt, As, Bs, acc, m0, n0, M, 512);
    const int fr = lane & 15;
    const int orow = (lane >> 4) * 4;
    #pragma unroll
    for (int m = 0; m < 4; ++m)
        #pragma unroll
        for (int j = 0; j < 4; ++j) {
            int r = m0 + wr * 64 + m * 16 + orow + j;
            if (r < M) {
                #pragma unroll
                for (int n = 0; n < 4; ++n) {
                    int ccol = n0 + wc * 64 + n * 16 + fr;
                    C[(size_t)r * CH + ccol] = acc[m][n][j] + bu[ccol] + xres[(size_t)r * CH + ccol];
                }
            }
        }
}

// ---------------------------------------------------------------------------
// Per-node attention logits from bf16 h
// ---------------------------------------------------------------------------
__global__ void alpha_kernel(const unsigned short* __restrict__ Hb,
                             const float* __restrict__ as1, const float* __restrict__ ad1,
                             const float* __restrict__ as2, const float* __restrict__ ad2,
                             float* __restrict__ alpha_src, float* __restrict__ alpha_dst, int N) {
    int wid = (blockIdx.x * blockDim.x + threadIdx.x) >> 6;
    int lane = threadIdx.x & 63;
    if (wid >= N) return;
    int c0 = lane * 8;
    const float* av_s = (c0 < 256) ? (as1 + c0) : (as2 + (c0 - 256));
    const float* av_d = (c0 < 256) ? (ad1 + c0) : (ad2 + (c0 - 256));
    int4 hv = *(const int4*)(Hb + (size_t)wid * CC + c0);
    float hh[8];
    hh[0] = bfbits((unsigned)hv.x & 0xffffu); hh[1] = bfbits((unsigned)hv.x >> 16);
    hh[2] = bfbits((unsigned)hv.y & 0xffffu); hh[3] = bfbits((unsigned)hv.y >> 16);
    hh[4] = bfbits((unsigned)hv.z & 0xffffu); hh[5] = bfbits((unsigned)hv.z >> 16);
    hh[6] = bfbits((unsigned)hv.w & 0xffffu); hh[7] = bfbits((unsigned)hv.w >> 16);
    float4 s0 = *(const float4*)(av_s), s1 = *(const float4*)(av_s + 4);
    float4 d0 = *(const float4*)(av_d), d1 = *(const float4*)(av_d + 4);
    float ps = hh[0] * s0.x + hh[1] * s0.y + hh[2] * s0.z + hh[3] * s0.w
             + hh[4] * s1.x + hh[5] * s1.y + hh[6] * s1.z + hh[7] * s1.w;
    float pd = hh[0] * d0.x + hh[1] * d0.y + hh[2] * d0.z + hh[3] * d0.w
             + hh[4] * d1.x + hh[5] * d1.y + hh[6] * d1.z + hh[7] * d1.w;
    ps += __shfl_xor(ps, 1); pd += __shfl_xor(pd, 1);
    ps += __shfl_xor(ps, 2); pd += __shfl_xor(pd, 2);
    float ps3 = ps + __shfl_xor(ps, 4);
    float pd3 = pd + __shfl_xor(pd, 4);
    if (lane < 32) {
        if ((lane & 7) == 0) {
            int hd = lane >> 3;
            alpha_src[(size_t)wid * NH + hd] = ps3;
            alpha_dst[(size_t)wid * NH + hd] = pd3;
        }
    } else {
        if ((lane & 3) == 0) {
            int hd = 4 + ((lane - 32) >> 2);
            alpha_src[(size_t)wid * NH + hd] = ps;
            alpha_dst[(size_t)wid * NH + hd] = pd;
        }
    }
}

// ---------------------------------------------------------------------------
// CSR build
// ---------------------------------------------------------------------------
__global__ void deg_init_kernel(int* __restrict__ deg, int N) {
    int i = blockIdx.x * blockDim.x + threadIdx.x;
    if (i < N) deg[i] = 1;
}
__global__ void hist_kernel(const int* __restrict__ dst, int* __restrict__ deg, int E) {
    int i = blockIdx.x * blockDim.x + threadIdx.x;
    if (i < E) atomicAdd(&deg[dst[i]], 1);
}
// scan1: per-1024 block exclusive prefix (256 thr x 4), shfl-based
__global__ __launch_bounds__(256) void scan1_kernel(const int* __restrict__ deg, int* __restrict__ pre,
                                                    int* __restrict__ bsum, int n) {
    __shared__ int wsum[4];
    int t = threadIdx.x, lane = t & 63, w = t >> 6;
    int base = blockIdx.x * 1024 + t * 4;
    int v0 = base     < n ? deg[base]     : 0;
    int v1 = base + 1 < n ? deg[base + 1] : 0;
    int v2 = base + 2 < n ? deg[base + 2] : 0;
    int v3 = base + 3 < n ? deg[base + 3] : 0;
    int s = v0 + v1 + v2 + v3;
    int sc = s;
    #pragma unroll
    for (int o = 1; o < 64; o <<= 1) { int xx = __shfl_up(sc, o); if (lane >= o) sc += xx; }
    if (lane == 63) wsum[w] = sc;
    __syncthreads();
    int wo = 0;
    #pragma unroll
    for (int k = 0; k < 4; ++k) if (k < w) wo += wsum[k];
    int p = wo + sc - s;
    if (base     < n) pre[base]     = p; p += v0;
    if (base + 1 < n) pre[base + 1] = p; p += v1;
    if (base + 2 < n) pre[base + 2] = p; p += v2;
    if (base + 3 < n) pre[base + 3] = p;
    if (t == 255) bsum[blockIdx.x] = wo + sc;
}
__global__ void scan2_kernel(int* __restrict__ bsum, int nb) {
    int lane = threadIdx.x;
    int v = lane < nb ? bsum[lane] : 0;
    int sc = v;
    #pragma unroll
    for (int o = 1; o < 64; o <<= 1) { int xx = __shfl_up(sc, o); if (lane >= o) sc += xx; }
    if (lane < nb) bsum[lane] = sc - v;
}
__global__ void scan3_kernel(const int* __restrict__ pre, const int* __restrict__ bsum,
                             int* __restrict__ offsets, int n, int total) {
    int i = blockIdx.x * 256 + threadIdx.x;
    if (i < n) offsets[i] = pre[i] + bsum[i >> 10];
    if (i == 0) offsets[n] = total;
}
__global__ void csr_init_kernel(const int* __restrict__ offsets, int* __restrict__ cursor,
                                int* __restrict__ csr, int N) {
    int i = blockIdx.x * blockDim.x + threadIdx.x;
    if (i < N) {
        int o = offsets[i];
        cursor[i] = o + 1;
        csr[o] = i;     // self-loop slot 0
    }
}
__global__ void scatter_kernel(const int* __restrict__ src, const int* __restrict__ dst,
                               int* __restrict__ cursor, int* __restrict__ csr, int E) {
    int i = blockIdx.x * blockDim.x + threadIdx.x;
    if (i < E) {
        int pos = atomicAdd(&cursor[dst[i]], 1);
        csr[pos] = src[i];
    }
}

// ---------------------------------------------------------------------------
// Aggregation (bf16 h gather): one wave per node; no max-pass (logits ~O(1))
// ---------------------------------------------------------------------------
__global__ void aggregate_kernel(const unsigned short* __restrict__ Hb,
                                 const float* __restrict__ alpha_src,
                                 const float* __restrict__ alpha_dst,
                                 const int* __restrict__ offsets,
                                 const int* __restrict__ csr,
                                 const float* __restrict__ b1, const float* __restrict__ b2,
                                 unsigned short* __restrict__ xcb, int N) {
    int n = (blockIdx.x * blockDim.x + threadIdx.x) >> 6;
    int lane = threadIdx.x & 63;
    if (n >= N) return;
    int beg = offsets[n], end = offsets[n + 1];

    float ssum = 0.f, ad = 0.f;
    if (lane < NH) {
        ad = alpha_dst[(size_t)n * NH + lane];
        for (int i = beg; i < end; ++i) {
            int s = csr[i];
            float lr = alpha_src[(size_t)s * NH + lane] + ad;
            lr = lr > 0.f ? lr : 0.2f * lr;
            ssum += __expf(lr);
        }
    }
    int c0 = lane * 8;
    int hid = (lane < 32) ? (lane >> 3) : (4 + ((lane - 32) >> 2));
    float dh  = __shfl(ssum, hid);
    float adh = __shfl(ad, hid);
    float inv = 1.0f / (dh + 1e-16f);

    float a0 = 0, a1 = 0, a2 = 0, a3 = 0, a4 = 0, a5 = 0, a6 = 0, a7 = 0;
    for (int i = beg; i < end; ++i) {
        int s = csr[i];
        float lr = alpha_src[(size_t)s * NH + hid] + adh;
        lr = lr > 0.f ? lr : 0.2f * lr;
        float wgt = __expf(lr) * inv;
        int4 hv = *(const int4*)(Hb + (size_t)s * CC + c0);
        a0 += wgt * bfbits((unsigned)hv.x & 0xffffu);
        a1 += wgt * bfbits((unsigned)hv.x >> 16);
        a2 += wgt * bfbits((unsigned)hv.y & 0xffffu);
        a3 += wgt * bfbits((unsigned)hv.y >> 16);
        a4 += wgt * bfbits((unsigned)hv.z & 0xffffu);
        a5 += wgt * bfbits((unsigned)hv.z >> 16);
        a6 += wgt * bfbits((unsigned)hv.w & 0xffffu);
        a7 += wgt * bfbits((unsigned)hv.w >> 16);
    }
    const float* bb = (c0 < 256) ? (b1 + c0) : (b2 + (c0 - 256));
    float4 bb0 = *(const float4*)(bb), bb1 = *(const float4*)(bb + 4);
    float o[8];
    o[0] = a0 + bb0.x; o[1] = a1 + bb0.y; o[2] = a2 + bb0.z; o[3] = a3 + bb0.w;
    o[4] = a4 + bb1.x; o[5] = a5 + bb1.y; o[6] = a6 + bb1.z; o[7] = a7 + bb1.w;
    #pragma unroll
    for (int j = 0; j < 8; ++j) o[j] = o[j] > 0.f ? o[j] : expm1f(o[j]);
    unsigned short u[8];
    #pragma unroll
    for (int j = 0; j < 8; ++j) u[j] = f2bf(o[j]);
    int4 pk;
    pk.x = (int)((unsigned)u[0] | ((unsigned)u[1] << 16));
    pk.y = (int)((unsigned)u[2] | ((unsigned)u[3] << 16));
    pk.z = (int)((unsigned)u[4] | ((unsigned)u[5] << 16));
    pk.w = (int)((unsigned)u[6] | ((unsigned)u[7] << 16));
    *(int4*)(xcb + (size_t)n * CC + c0) = pk;
}

// ---------------------------------------------------------------------------
// Launch
// ---------------------------------------------------------------------------
extern "C" void kernel_launch(void* const* d_in, const int* in_sizes, int n_in,
                              void* d_out, int out_size, void* d_ws, size_t ws_size,
                              hipStream_t stream) {
    const float* x     = (const float*)d_in[0];
    const int*   ei    = (const int*)d_in[1];
    const float* gamma = (const float*)d_in[2];
    const float* beta  = (const float*)d_in[3];
    const float* W1    = (const float*)d_in[4];
    const float* as1   = (const float*)d_in[5];
    const float* ad1   = (const float*)d_in[6];
    const float* b1    = (const float*)d_in[7];
    const float* W2    = (const float*)d_in[8];
    const float* as2   = (const float*)d_in[9];
    const float* ad2   = (const float*)d_in[10];
    const float* b2    = (const float*)d_in[11];
    const float* Wu    = (const float*)d_in[12];
    const float* bu    = (const float*)d_in[13];
    float* out = (float*)d_out;

    const int N = in_sizes[0] / CH;
    const int E = in_sizes[1] / 2;
    const int* src = ei;
    const int* dst = ei + E;

    char* w = (char*)d_ws;
    auto alloc = [&](size_t bytes) { char* p = w; w += (bytes + 255) & ~(size_t)255; return p; };
    unsigned short* Hb  = (unsigned short*)alloc((size_t)N * CC * 2);
    unsigned short* xnb = (unsigned short*)alloc((size_t)N * CH * 2);
    unsigned short* xcb = (unsigned short*)alloc((size_t)N * CC * 2);
    unsigned short* WT1 = (unsigned short*)alloc(512 * 256 * 2);
    unsigned short* WTu = (unsigned short*)alloc(256 * 512 * 2);
    float* alpha_src = (float*)alloc((size_t)N * NH * 4);
    float* alpha_dst = (float*)alloc((size_t)N * NH * 4);
    int* deg     = (int*)alloc((size_t)N * 4);
    int* pre     = (int*)alloc((size_t)N * 4);
    int* bsum    = (int*)alloc(64 * 4);
    int* offsets = (int*)alloc(((size_t)N + 1) * 4);
    int* cursor  = (int*)alloc((size_t)N * 4);
    int* csr     = (int*)alloc(((size_t)E + N) * 4);

    ln_kernel<<<(N + 3) / 4, 256, 0, stream>>>(x, gamma, beta, xnb, N);
    prep_wt1_kernel<<<512, 256, 0, stream>>>(W1, W2, WT1);
    prep_wtu_kernel<<<512, 256, 0, stream>>>(Wu, WTu);

    dim3 g1(4, (N + 127) / 128);
    gemm1_mfma<<<g1, 256, 0, stream>>>(xnb, WT1, Hb, N);

    alpha_kernel<<<(N + 3) / 4, 256, 0, stream>>>(Hb, as1, ad1, as2, ad2, alpha_src, alpha_dst, N);

    deg_init_kernel<<<(N + 255) / 256, 256, 0, stream>>>(deg, N);
    hist_kernel<<<(E + 255) / 256, 256, 0, stream>>>(dst, deg, E);
    int nb = (N + 1023) / 1024;
    scan1_kernel<<<nb, 256, 0, stream>>>(deg, pre, bsum, N);
    scan2_kernel<<<1, 64, 0, stream>>>(bsum, nb);
    scan3_kernel<<<(N + 255) / 256, 256, 0, stream>>>(pre, bsum, offsets, N, E + N);
    csr_init_kernel<<<(N + 255) / 256, 256, 0, stream>>>(offsets, cursor, csr, N);
    scatter_kernel<<<(E + 255) / 256, 256, 0, stream>>>(src, dst, cursor, csr, E);

    aggregate_kernel<<<(N + 3) / 4, 256, 0, stream>>>(Hb, alpha_src, alpha_dst, offsets, csr,
                                                      b1, b2, xcb, N);

    dim3 g2(2, (N + 127) / 128);
    gemm2_mfma<<<g2, 256, 0, stream>>>(xcb, WTu, bu, x, out, N);
}

// Round 3
// 246.602 us; speedup vs baseline: 2.9684x; 1.1863x over previous
//
#include <hip/hip_runtime.h>
#include <hip/hip_bf16.h>
#include <math.h>

constexpr int CH = 256;       // input channels
constexpr int CC = 512;       // concat width
constexpr int NH = 12;        // total heads (4 + 8)

typedef __bf16 bf16x8 __attribute__((ext_vector_type(8)));
typedef float  f32x4  __attribute__((ext_vector_type(4)));
typedef __attribute__((address_space(3))) void lds_void;
typedef __attribute__((address_space(1))) void glb_void;

__device__ inline unsigned short f2bf(float f) {
    union { float f; unsigned u; } v; v.f = f;
    unsigned r = v.u + 0x7FFFu + ((v.u >> 16) & 1u);
    return (unsigned short)(r >> 16);
}
__device__ inline float bfbits(unsigned lo16) {
    union { unsigned u; float f; } v; v.u = lo16 << 16;
    return v.f;
}

// ---------------------------------------------------------------------------
// LayerNorm -> bf16: one wave per row
// ---------------------------------------------------------------------------
__global__ void ln_kernel(const float* __restrict__ x, const float* __restrict__ gamma,
                          const float* __restrict__ beta, unsigned short* __restrict__ xnb, int N) {
    int wid = (blockIdx.x * blockDim.x + threadIdx.x) >> 6;
    int lane = threadIdx.x & 63;
    if (wid >= N) return;
    const float4 v = *(const float4*)(x + (size_t)wid * CH + lane * 4);
    float s = v.x + v.y + v.z + v.w;
    float sq = v.x * v.x + v.y * v.y + v.z * v.z + v.w * v.w;
    #pragma unroll
    for (int o = 32; o; o >>= 1) { s += __shfl_xor(s, o); sq += __shfl_xor(sq, o); }
    float mu = s * (1.0f / CH);
    float var = sq * (1.0f / CH) - mu * mu;
    float rs = rsqrtf(var + 1e-5f);
    float4 g = *(const float4*)(gamma + lane * 4);
    float4 b = *(const float4*)(beta + lane * 4);
    unsigned short o0 = f2bf((v.x - mu) * rs * g.x + b.x);
    unsigned short o1 = f2bf((v.y - mu) * rs * g.y + b.y);
    unsigned short o2 = f2bf((v.z - mu) * rs * g.z + b.z);
    unsigned short o3 = f2bf((v.w - mu) * rs * g.w + b.w);
    uint2 pk;
    pk.x = (unsigned)o0 | ((unsigned)o1 << 16);
    pk.y = (unsigned)o2 | ((unsigned)o3 << 16);
    *(uint2*)(xnb + (size_t)wid * CH + lane * 4) = pk;
}

// ---------------------------------------------------------------------------
// Weight prep: transpose + convert to bf16
// ---------------------------------------------------------------------------
__global__ void prep_wt1_kernel(const float* __restrict__ W1, const float* __restrict__ W2,
                                unsigned short* __restrict__ WT) {
    int idx = blockIdx.x * 256 + threadIdx.x;      // over 512*256
    if (idx >= 512 * 256) return;
    int n = idx >> 8, k = idx & 255;
    float v = (n < 256) ? W1[(size_t)k * 256 + n] : W2[(size_t)k * 256 + (n - 256)];
    WT[idx] = f2bf(v);
}
__global__ void prep_wtu_kernel(const float* __restrict__ Wu, unsigned short* __restrict__ WT) {
    int idx = blockIdx.x * 256 + threadIdx.x;      // over 256*512
    if (idx >= 256 * 512) return;
    int n = idx >> 9, k = idx & 511;
    WT[idx] = f2bf(Wu[(size_t)k * 256 + n]);
}

// ---------------------------------------------------------------------------
// bf16 MFMA GEMM, 128x128 tile, BK=64, 4 waves (each 64x64 out)
// LDS XOR-swizzle: physical colbyte = logical ^ ((row&7)<<4); staged via
// inverse-swizzled global source (global_load_lds writes linearly).
// ---------------------------------------------------------------------------
__device__ inline void gemm_core(const unsigned short* __restrict__ Ab,
                                 const unsigned short* __restrict__ Bt,
                                 unsigned short* As, unsigned short* Bs,
                                 f32x4 acc[4][4], int m0, int n0, int M, int K) {
    const int t = threadIdx.x;
    const int lane = t & 63;
    const int wave = t >> 6;
    const int wr = wave >> 1, wc = wave & 1;
    const int srow = lane >> 3;                        // 0..7
    const int scol = (((lane & 7) ^ srow) << 3);       // inverse-swizzled elem col
    const int fr = lane & 15;
    const int fkb = (lane >> 4) << 4;                  // logical colbyte per 16-lane group

    for (int k0 = 0; k0 < K; k0 += 64) {
        __syncthreads();
        #pragma unroll
        for (int c = 0; c < 4; ++c) {
            int chunk = c * 4 + wave;                  // 0..15 -> 8 rows each
            int row = chunk * 8 + srow;                // 0..127
            int gra = m0 + row; if (gra >= M) gra = M - 1;
            const unsigned short* ga = Ab + (size_t)gra * K + k0 + scol;
            __builtin_amdgcn_global_load_lds((const glb_void*)ga,
                                             (lds_void*)&As[chunk * 512], 16, 0, 0);
            const unsigned short* gb = Bt + (size_t)(n0 + row) * K + k0 + scol;
            __builtin_amdgcn_global_load_lds((const glb_void*)gb,
                                             (lds_void*)&Bs[chunk * 512], 16, 0, 0);
        }
        __syncthreads();
        #pragma unroll
        for (int ks = 0; ks < 2; ++ks) {
            bf16x8 af[4], bfr[4];
            #pragma unroll
            for (int m = 0; m < 4; ++m) {
                int r = wr * 64 + m * 16 + fr;
                int cb = (ks * 64 + fkb) ^ ((r & 7) << 4);
                af[m] = *(const bf16x8*)((const char*)As + r * 128 + cb);
            }
            #pragma unroll
            for (int n = 0; n < 4; ++n) {
                int r = wc * 64 + n * 16 + fr;
                int cb = (ks * 64 + fkb) ^ ((r & 7) << 4);
                bfr[n] = *(const bf16x8*)((const char*)Bs + r * 128 + cb);
            }
            #pragma unroll
            for (int m = 0; m < 4; ++m)
                #pragma unroll
                for (int n = 0; n < 4; ++n)
                    acc[m][n] = __builtin_amdgcn_mfma_f32_16x16x32_bf16(af[m], bfr[n], acc[m][n], 0, 0, 0);
        }
    }
}

// GEMM1: h(bf16)[M,512] = xnorm(bf16)[M,256] @ W(bf16,T)[512,256]^T
__global__ __launch_bounds__(256) void gemm1_mfma(const unsigned short* __restrict__ Ab,
                                                  const unsigned short* __restrict__ Bt,
                                                  unsigned short* __restrict__ H, int M) {
    __shared__ unsigned short As[128 * 64];
    __shared__ unsigned short Bs[128 * 64];
    const int lane = threadIdx.x & 63;
    const int wave = threadIdx.x >> 6;
    const int wr = wave >> 1, wc = wave & 1;
    const int m0 = blockIdx.y * 128, n0 = blockIdx.x * 128;
    f32x4 acc[4][4] = {};
    gemm_core(Ab, Bt, As, Bs, acc, m0, n0, M, 256);
    const int fr = lane & 15;
    const int orow = (lane >> 4) * 4;
    #pragma unroll
    for (int m = 0; m < 4; ++m)
        #pragma unroll
        for (int j = 0; j < 4; ++j) {
            int r = m0 + wr * 64 + m * 16 + orow + j;
            if (r < M) {
                #pragma unroll
                for (int n = 0; n < 4; ++n) {
                    int ccol = n0 + wc * 64 + n * 16 + fr;
                    H[(size_t)r * CC + ccol] = f2bf(acc[m][n][j]);
                }
            }
        }
}

// GEMM2: out(f32)[M,256] = x + xcat(bf16)[M,512] @ Wu(bf16,T)[256,512]^T + bu
__global__ __launch_bounds__(256) void gemm2_mfma(const unsigned short* __restrict__ Ab,
                                                  const unsigned short* __restrict__ Bt,
                                                  const float* __restrict__ bu,
                                                  const float* __restrict__ xres,
                                                  float* __restrict__ C, int M) {
    __shared__ unsigned short As[128 * 64];
    __shared__ unsigned short Bs[128 * 64];
    const int lane = threadIdx.x & 63;
    const int wave = threadIdx.x >> 6;
    const int wr = wave >> 1, wc = wave & 1;
    const int m0 = blockIdx.y * 128, n0 = blockIdx.x * 128;
    f32x4 acc[4][4] = {};
    gemm_core(Ab, Bt, As, Bs, acc, m0, n0, M, 512);
    const int fr = lane & 15;
    const int orow = (lane >> 4) * 4;
    #pragma unroll
    for (int m = 0; m < 4; ++m)
        #pragma unroll
        for (int j = 0; j < 4; ++j) {
            int r = m0 + wr * 64 + m * 16 + orow + j;
            if (r < M) {
                #pragma unroll
                for (int n = 0; n < 4; ++n) {
                    int ccol = n0 + wc * 64 + n * 16 + fr;
                    C[(size_t)r * CH + ccol] = acc[m][n][j] + bu[ccol] + xres[(size_t)r * CH + ccol];
                }
            }
        }
}

// ---------------------------------------------------------------------------
// Per-node attention logits from bf16 h
// ---------------------------------------------------------------------------
__global__ void alpha_kernel(const unsigned short* __restrict__ Hb,
                             const float* __restrict__ as1, const float* __restrict__ ad1,
                             const float* __restrict__ as2, const float* __restrict__ ad2,
                             float* __restrict__ alpha_src, float* __restrict__ alpha_dst, int N) {
    int wid = (blockIdx.x * blockDim.x + threadIdx.x) >> 6;
    int lane = threadIdx.x & 63;
    if (wid >= N) return;
    int c0 = lane * 8;
    const float* av_s = (c0 < 256) ? (as1 + c0) : (as2 + (c0 - 256));
    const float* av_d = (c0 < 256) ? (ad1 + c0) : (ad2 + (c0 - 256));
    int4 hv = *(const int4*)(Hb + (size_t)wid * CC + c0);
    float hh[8];
    hh[0] = bfbits((unsigned)hv.x & 0xffffu); hh[1] = bfbits((unsigned)hv.x >> 16);
    hh[2] = bfbits((unsigned)hv.y & 0xffffu); hh[3] = bfbits((unsigned)hv.y >> 16);
    hh[4] = bfbits((unsigned)hv.z & 0xffffu); hh[5] = bfbits((unsigned)hv.z >> 16);
    hh[6] = bfbits((unsigned)hv.w & 0xffffu); hh[7] = bfbits((unsigned)hv.w >> 16);
    float4 s0 = *(const float4*)(av_s), s1 = *(const float4*)(av_s + 4);
    float4 d0 = *(const float4*)(av_d), d1 = *(const float4*)(av_d + 4);
    float ps = hh[0] * s0.x + hh[1] * s0.y + hh[2] * s0.z + hh[3] * s0.w
             + hh[4] * s1.x + hh[5] * s1.y + hh[6] * s1.z + hh[7] * s1.w;
    float pd = hh[0] * d0.x + hh[1] * d0.y + hh[2] * d0.z + hh[3] * d0.w
             + hh[4] * d1.x + hh[5] * d1.y + hh[6] * d1.z + hh[7] * d1.w;
    ps += __shfl_xor(ps, 1); pd += __shfl_xor(pd, 1);
    ps += __shfl_xor(ps, 2); pd += __shfl_xor(pd, 2);
    float ps3 = ps + __shfl_xor(ps, 4);
    float pd3 = pd + __shfl_xor(pd, 4);
    if (lane < 32) {
        if ((lane & 7) == 0) {
            int hd = lane >> 3;
            alpha_src[(size_t)wid * NH + hd] = ps3;
            alpha_dst[(size_t)wid * NH + hd] = pd3;
        }
    } else {
        if ((lane & 3) == 0) {
            int hd = 4 + ((lane - 32) >> 2);
            alpha_src[(size_t)wid * NH + hd] = ps;
            alpha_dst[(size_t)wid * NH + hd] = pd;
        }
    }
}

// ---------------------------------------------------------------------------
// CSR build
// ---------------------------------------------------------------------------
__global__ void deg_init_kernel(int* __restrict__ deg, int N) {
    int i = blockIdx.x * blockDim.x + threadIdx.x;
    if (i < N) deg[i] = 1;
}
__global__ void hist_kernel(const int* __restrict__ dst, int* __restrict__ deg, int E) {
    int i = blockIdx.x * blockDim.x + threadIdx.x;
    if (i < E) atomicAdd(&deg[dst[i]], 1);
}
__global__ __launch_bounds__(256) void scan1_kernel(const int* __restrict__ deg, int* __restrict__ pre,
                                                    int* __restrict__ bsum, int n) {
    __shared__ int wsum[4];
    int t = threadIdx.x, lane = t & 63, w = t >> 6;
    int base = blockIdx.x * 1024 + t * 4;
    int v0 = base     < n ? deg[base]     : 0;
    int v1 = base + 1 < n ? deg[base + 1] : 0;
    int v2 = base + 2 < n ? deg[base + 2] : 0;
    int v3 = base + 3 < n ? deg[base + 3] : 0;
    int s = v0 + v1 + v2 + v3;
    int sc = s;
    #pragma unroll
    for (int o = 1; o < 64; o <<= 1) { int xx = __shfl_up(sc, o); if (lane >= o) sc += xx; }
    if (lane == 63) wsum[w] = sc;
    __syncthreads();
    int wo = 0;
    #pragma unroll
    for (int k = 0; k < 4; ++k) if (k < w) wo += wsum[k];
    int p = wo + sc - s;
    if (base     < n) pre[base]     = p; p += v0;
    if (base + 1 < n) pre[base + 1] = p; p += v1;
    if (base + 2 < n) pre[base + 2] = p; p += v2;
    if (base + 3 < n) pre[base + 3] = p;
    if (t == 255) bsum[blockIdx.x] = wo + sc;
}
__global__ void scan2_kernel(int* __restrict__ bsum, int nb) {
    int lane = threadIdx.x;
    int v = lane < nb ? bsum[lane] : 0;
    int sc = v;
    #pragma unroll
    for (int o = 1; o < 64; o <<= 1) { int xx = __shfl_up(sc, o); if (lane >= o) sc += xx; }
    if (lane < nb) bsum[lane] = sc - v;
}
__global__ void scan3_kernel(const int* __restrict__ pre, const int* __restrict__ bsum,
                             int* __restrict__ offsets, int n, int total) {
    int i = blockIdx.x * 256 + threadIdx.x;
    if (i < n) offsets[i] = pre[i] + bsum[i >> 10];
    if (i == 0) offsets[n] = total;
}
__global__ void csr_init_kernel(const int* __restrict__ offsets, int* __restrict__ cursor,
                                int* __restrict__ csr, int N) {
    int i = blockIdx.x * blockDim.x + threadIdx.x;
    if (i < N) {
        int o = offsets[i];
        cursor[i] = o + 1;
        csr[o] = i;     // self-loop slot 0
    }
}
__global__ void scatter_kernel(const int* __restrict__ src, const int* __restrict__ dst,
                               int* __restrict__ cursor, int* __restrict__ csr, int E) {
    int i = blockIdx.x * blockDim.x + threadIdx.x;
    if (i < E) {
        int pos = atomicAdd(&cursor[dst[i]], 1);
        csr[pos] = src[i];
    }
}

// ---------------------------------------------------------------------------
// Aggregation: SINGLE edge pass. Post-normalization (no max-pass): each lane
// accumulates unnormalized Σw·h and its own Σw (identical within head group),
// divides at the end. 2x unrolled for memory-level parallelism.
// ---------------------------------------------------------------------------
__global__ void aggregate_kernel(const unsigned short* __restrict__ Hb,
                                 const float* __restrict__ alpha_src,
                                 const float* __restrict__ alpha_dst,
                                 const int* __restrict__ offsets,
                                 const int* __restrict__ csr,
                                 const float* __restrict__ b1, const float* __restrict__ b2,
                                 unsigned short* __restrict__ xcb, int N) {
    int n = (blockIdx.x * blockDim.x + threadIdx.x) >> 6;
    int lane = threadIdx.x & 63;
    if (n >= N) return;
    int beg = offsets[n], end = offsets[n + 1];
    int c0 = lane * 8;
    int hid = (lane < 32) ? (lane >> 3) : (4 + ((lane - 32) >> 2));
    float adh = alpha_dst[(size_t)n * NH + hid];

    float ssum = 0.f;
    float a0 = 0, a1 = 0, a2 = 0, a3 = 0, a4 = 0, a5 = 0, a6 = 0, a7 = 0;

    int i = beg;
    for (; i + 1 < end; i += 2) {
        int s0 = csr[i], s1 = csr[i + 1];
        float l0 = alpha_src[(size_t)s0 * NH + hid] + adh;
        float l1 = alpha_src[(size_t)s1 * NH + hid] + adh;
        int4 hv0 = *(const int4*)(Hb + (size_t)s0 * CC + c0);
        int4 hv1 = *(const int4*)(Hb + (size_t)s1 * CC + c0);
        l0 = l0 > 0.f ? l0 : 0.2f * l0;
        l1 = l1 > 0.f ? l1 : 0.2f * l1;
        float w0 = __expf(l0), w1 = __expf(l1);
        ssum += w0 + w1;
        a0 += w0 * bfbits((unsigned)hv0.x & 0xffffu) + w1 * bfbits((unsigned)hv1.x & 0xffffu);
        a1 += w0 * bfbits((unsigned)hv0.x >> 16)     + w1 * bfbits((unsigned)hv1.x >> 16);
        a2 += w0 * bfbits((unsigned)hv0.y & 0xffffu) + w1 * bfbits((unsigned)hv1.y & 0xffffu);
        a3 += w0 * bfbits((unsigned)hv0.y >> 16)     + w1 * bfbits((unsigned)hv1.y >> 16);
        a4 += w0 * bfbits((unsigned)hv0.z & 0xffffu) + w1 * bfbits((unsigned)hv1.z & 0xffffu);
        a5 += w0 * bfbits((unsigned)hv0.z >> 16)     + w1 * bfbits((unsigned)hv1.z >> 16);
        a6 += w0 * bfbits((unsigned)hv0.w & 0xffffu) + w1 * bfbits((unsigned)hv1.w & 0xffffu);
        a7 += w0 * bfbits((unsigned)hv0.w >> 16)     + w1 * bfbits((unsigned)hv1.w >> 16);
    }
    if (i < end) {
        int s0 = csr[i];
        float l0 = alpha_src[(size_t)s0 * NH + hid] + adh;
        int4 hv0 = *(const int4*)(Hb + (size_t)s0 * CC + c0);
        l0 = l0 > 0.f ? l0 : 0.2f * l0;
        float w0 = __expf(l0);
        ssum += w0;
        a0 += w0 * bfbits((unsigned)hv0.x & 0xffffu);
        a1 += w0 * bfbits((unsigned)hv0.x >> 16);
        a2 += w0 * bfbits((unsigned)hv0.y & 0xffffu);
        a3 += w0 * bfbits((unsigned)hv0.y >> 16);
        a4 += w0 * bfbits((unsigned)hv0.z & 0xffffu);
        a5 += w0 * bfbits((unsigned)hv0.z >> 16);
        a6 += w0 * bfbits((unsigned)hv0.w & 0xffffu);
        a7 += w0 * bfbits((unsigned)hv0.w >> 16);
    }

    float inv = 1.0f / (ssum + 1e-16f);
    const float* bb = (c0 < 256) ? (b1 + c0) : (b2 + (c0 - 256));
    float4 bb0 = *(const float4*)(bb), bb1 = *(const float4*)(bb + 4);
    float o[8];
    o[0] = a0 * inv + bb0.x; o[1] = a1 * inv + bb0.y; o[2] = a2 * inv + bb0.z; o[3] = a3 * inv + bb0.w;
    o[4] = a4 * inv + bb1.x; o[5] = a5 * inv + bb1.y; o[6] = a6 * inv + bb1.z; o[7] = a7 * inv + bb1.w;
    #pragma unroll
    for (int j = 0; j < 8; ++j) o[j] = o[j] > 0.f ? o[j] : expm1f(o[j]);
    unsigned short u[8];
    #pragma unroll
    for (int j = 0; j < 8; ++j) u[j] = f2bf(o[j]);
    int4 pk;
    pk.x = (int)((unsigned)u[0] | ((unsigned)u[1] << 16));
    pk.y = (int)((unsigned)u[2] | ((unsigned)u[3] << 16));
    pk.z = (int)((unsigned)u[4] | ((unsigned)u[5] << 16));
    pk.w = (int)((unsigned)u[6] | ((unsigned)u[7] << 16));
    *(int4*)(xcb + (size_t)n * CC + c0) = pk;
}

// ---------------------------------------------------------------------------
// Launch
// ---------------------------------------------------------------------------
extern "C" void kernel_launch(void* const* d_in, const int* in_sizes, int n_in,
                              void* d_out, int out_size, void* d_ws, size_t ws_size,
                              hipStream_t stream) {
    const float* x     = (const float*)d_in[0];
    const int*   ei    = (const int*)d_in[1];
    const float* gamma = (const float*)d_in[2];
    const float* beta  = (const float*)d_in[3];
    const float* W1    = (const float*)d_in[4];
    const float* as1   = (const float*)d_in[5];
    const float* ad1   = (const float*)d_in[6];
    const float* b1    = (const float*)d_in[7];
    const float* W2    = (const float*)d_in[8];
    const float* as2   = (const float*)d_in[9];
    const float* ad2   = (const float*)d_in[10];
    const float* b2    = (const float*)d_in[11];
    const float* Wu    = (const float*)d_in[12];
    const float* bu    = (const float*)d_in[13];
    float* out = (float*)d_out;

    const int N = in_sizes[0] / CH;
    const int E = in_sizes[1] / 2;
    const int* src = ei;
    const int* dst = ei + E;

    char* w = (char*)d_ws;
    auto alloc = [&](size_t bytes) { char* p = w; w += (bytes + 255) & ~(size_t)255; return p; };
    unsigned short* Hb  = (unsigned short*)alloc((size_t)N * CC * 2);
    unsigned short* xnb = (unsigned short*)alloc((size_t)N * CH * 2);
    unsigned short* xcb = (unsigned short*)alloc((size_t)N * CC * 2);
    unsigned short* WT1 = (unsigned short*)alloc(512 * 256 * 2);
    unsigned short* WTu = (unsigned short*)alloc(256 * 512 * 2);
    float* alpha_src = (float*)alloc((size_t)N * NH * 4);
    float* alpha_dst = (float*)alloc((size_t)N * NH * 4);
    int* deg     = (int*)alloc((size_t)N * 4);
    int* pre     = (int*)alloc((size_t)N * 4);
    int* bsum    = (int*)alloc(64 * 4);
    int* offsets = (int*)alloc(((size_t)N + 1) * 4);
    int* cursor  = (int*)alloc((size_t)N * 4);
    int* csr     = (int*)alloc(((size_t)E + N) * 4);

    ln_kernel<<<(N + 3) / 4, 256, 0, stream>>>(x, gamma, beta, xnb, N);
    prep_wt1_kernel<<<512, 256, 0, stream>>>(W1, W2, WT1);
    prep_wtu_kernel<<<512, 256, 0, stream>>>(Wu, WTu);

    dim3 g1(4, (N + 127) / 128);
    gemm1_mfma<<<g1, 256, 0, stream>>>(xnb, WT1, Hb, N);

    alpha_kernel<<<(N + 3) / 4, 256, 0, stream>>>(Hb, as1, ad1, as2, ad2, alpha_src, alpha_dst, N);

    deg_init_kernel<<<(N + 255) / 256, 256, 0, stream>>>(deg, N);
    hist_kernel<<<(E + 255) / 256, 256, 0, stream>>>(dst, deg, E);
    int nb = (N + 1023) / 1024;
    scan1_kernel<<<nb, 256, 0, stream>>>(deg, pre, bsum, N);
    scan2_kernel<<<1, 64, 0, stream>>>(bsum, nb);
    scan3_kernel<<<(N + 255) / 256, 256, 0, stream>>>(pre, bsum, offsets, N, E + N);
    csr_init_kernel<<<(N + 255) / 256, 256, 0, stream>>>(offsets, cursor, csr, N);
    scatter_kernel<<<(E + 255) / 256, 256, 0, stream>>>(src, dst, cursor, csr, E);

    aggregate_kernel<<<(N + 3) / 4, 256, 0, stream>>>(Hb, alpha_src, alpha_dst, offsets, csr,
                                                      b1, b2, xcb, N);

    dim3 g2(2, (N + 127) / 128);
    gemm2_mfma<<<g2, 256, 0, stream>>>(xcb, WTu, bu, x, out, N);
}